// Round 1
// baseline (930.005 us; speedup 1.0000x reference)
//
#include <hip/hip_runtime.h>
#include <hip/hip_bf16.h>
#include <cstdint>
#include <cstddef>

// MoE: T=2048 tokens, D=2048, INNER=5632, E=8, top-2 routing.
// Sparse (routed) computation == dense reference since expert_w is 0 for
// unselected experts.

#define TOKS  2048
#define DIMSZ 2048
#define INNER 5632
#define NEXP  8

typedef __attribute__((ext_vector_type(8))) short short8;
typedef __attribute__((ext_vector_type(4))) float f32x4;

__device__ __forceinline__ unsigned short f2bf(float f) {
  __hip_bfloat16 b = __float2bfloat16(f);   // RNE; compiler uses v_cvt_pk_bf16_f32
  return __builtin_bit_cast(unsigned short, b);
}

__device__ __forceinline__ short8 pack8(float4 a, float4 b) {
  short8 s;
  s[0] = (short)f2bf(a.x); s[1] = (short)f2bf(a.y);
  s[2] = (short)f2bf(a.z); s[3] = (short)f2bf(a.w);
  s[4] = (short)f2bf(b.x); s[5] = (short)f2bf(b.y);
  s[6] = (short)f2bf(b.z); s[7] = (short)f2bf(b.w);
  return s;
}

// ---------------- router: logits -> softmax -> top2 -> renorm ---------------
__global__ void __launch_bounds__(64)
router_kernel(const float* __restrict__ x, const float* __restrict__ gw,
              int* __restrict__ sel, float* __restrict__ wts) {
  const int t = blockIdx.x;
  const int l = threadIdx.x;
  const float* xr = x + (size_t)t * DIMSZ;
  float xv[32];
#pragma unroll
  for (int i = 0; i < 32; ++i) xv[i] = xr[l + 64 * i];
  float lg[NEXP];
#pragma unroll
  for (int e = 0; e < NEXP; ++e) {
    const float* gr = gw + e * DIMSZ;
    float s = 0.f;
#pragma unroll
    for (int i = 0; i < 32; ++i) s += xv[i] * gr[l + 64 * i];
#pragma unroll
    for (int off = 32; off > 0; off >>= 1) s += __shfl_down(s, off, 64);
    lg[e] = s;  // complete on lane 0
  }
  if (l == 0) {
    float m = lg[0];
#pragma unroll
    for (int e = 1; e < NEXP; ++e) m = fmaxf(m, lg[e]);
    float p[NEXP];
#pragma unroll
    for (int e = 0; e < NEXP; ++e) p[e] = __expf(lg[e] - m);
    int i1 = 0;
#pragma unroll
    for (int e = 1; e < NEXP; ++e) if (p[e] > p[i1]) i1 = e;
    int i2 = (i1 == 0) ? 1 : 0;
#pragma unroll
    for (int e = 0; e < NEXP; ++e) if (e != i1 && p[e] > p[i2]) i2 = e;
    float den = p[i1] + p[i2];
    sel[2 * t] = i1; sel[2 * t + 1] = i2;
    wts[2 * t] = p[i1] / den; wts[2 * t + 1] = p[i2] / den;
  }
}

// ---- compaction: per-expert token lists, deterministic (slot order) --------
__global__ void __launch_bounds__(512)
compact_kernel(const int* __restrict__ sel, const float* __restrict__ wts,
               int* __restrict__ cnt, int* __restrict__ offs,
               int* __restrict__ tok, float* __restrict__ twt) {
  const int w = threadIdx.x >> 6;   // wave id == expert id
  const int l = threadIdx.x & 63;
  int c = 0;
  for (int base = 0; base < 2 * TOKS; base += 64) {
    int s = base + l;
    bool m = (sel[s] == w);
    unsigned long long mask = __ballot(m);
    int pre = __popcll(mask & ((1ull << l) - 1ull));
    if (m) {
      tok[w * TOKS + c + pre] = s >> 1;
      twt[w * TOKS + c + pre] = wts[s];
    }
    c += __popcll(mask);
  }
  if (l == 0) cnt[w] = c;
  __syncthreads();
  if (threadIdx.x == 0) {
    int acc = 0;
    for (int e = 0; e < NEXP; ++e) { offs[e] = acc; acc += cnt[e]; }
  }
}

// ---------------- x (fp32) -> bf16 ------------------------------------------
__global__ void __launch_bounds__(256)
cvtx_kernel(const float* __restrict__ x, unsigned short* __restrict__ xbf) {
  const int i = blockIdx.x * 256 + threadIdx.x;
  const float4* src = (const float4*)x;
  float4 a = src[2 * i], b = src[2 * i + 1];
  ((short8*)xbf)[i] = pack8(a, b);
}

// ------- GEMM1 fused: h = silu(x·w1^T) * (x·w3^T), per expert ---------------
// 128x128 tile, BK=64 bf16, 4 waves 2x2, XOR-swizzled LDS (16B groups).
__global__ void __launch_bounds__(256, 2)
gemm1_kernel(const unsigned short* __restrict__ xbf,
             const float* __restrict__ w1, const float* __restrict__ w3,
             const int* __restrict__ cnt, const int* __restrict__ offs,
             const int* __restrict__ tok, unsigned short* __restrict__ h) {
  const int e = blockIdx.z;
  const int n_e = cnt[e];
  const int by = blockIdx.y;
  if (by * 128 >= n_e) return;
  const int n0 = blockIdx.x * 128;
  const int tid = threadIdx.x;
  const int lane = tid & 63;
  const int wid = tid >> 6;
  const int wm = wid >> 1, wn = wid & 1;

  __shared__ short8 As[1024];   // [128 rows][8 groups of 8 bf16]
  __shared__ short8 B1s[1024];
  __shared__ short8 B3s[1024];

  // A staging: 4 reps x 256 threads x 16B, gathered token rows
  const unsigned short* asrc[4];
  int adst[4];
#pragma unroll
  for (int rep = 0; rep < 4; ++rep) {
    int flat = rep * 256 + tid;
    int row = flat >> 3, g = flat & 7;
    int ri = by * 128 + row;
    if (ri >= n_e) ri = n_e - 1;          // clamp (dummy rows, not stored)
    int tkn = tok[e * TOKS + ri];
    asrc[rep] = xbf + (size_t)tkn * DIMSZ + g * 8;
    adst[rep] = row * 8 + (g ^ (row & 7));
  }
  // B staging: fp32 -> bf16 in-register. 2 reps: row = rep*64 + tid/4,
  // each thread 16 floats (2 groups).
  const float* w1e = w1 + (size_t)e * INNER * DIMSZ;
  const float* w3e = w3 + (size_t)e * INNER * DIMSZ;
  const float* b1src[2]; const float* b3src[2];
  int bd0[2], bd1[2];
#pragma unroll
  for (int rep = 0; rep < 2; ++rep) {
    int row = rep * 64 + (tid >> 2);
    int gb = (tid & 3) * 2;
    b1src[rep] = w1e + (size_t)(n0 + row) * DIMSZ + gb * 8;
    b3src[rep] = w3e + (size_t)(n0 + row) * DIMSZ + gb * 8;
    bd0[rep] = row * 8 + (gb ^ (row & 7));
    bd1[rep] = row * 8 + ((gb + 1) ^ (row & 7));
  }

  f32x4 acc1[4][4] = {};
  f32x4 acc3[4][4] = {};

#pragma unroll 1
  for (int k0 = 0; k0 < DIMSZ; k0 += 64) {
#pragma unroll
    for (int rep = 0; rep < 4; ++rep)
      As[adst[rep]] = *(const short8*)(asrc[rep] + k0);
#pragma unroll
    for (int rep = 0; rep < 2; ++rep) {
      const float4* p = (const float4*)(b1src[rep] + k0);
      float4 a0 = p[0], a1 = p[1], a2 = p[2], a3 = p[3];
      B1s[bd0[rep]] = pack8(a0, a1);
      B1s[bd1[rep]] = pack8(a2, a3);
      const float4* q = (const float4*)(b3src[rep] + k0);
      float4 c0 = q[0], c1 = q[1], c2 = q[2], c3 = q[3];
      B3s[bd0[rep]] = pack8(c0, c1);
      B3s[bd1[rep]] = pack8(c2, c3);
    }
    __syncthreads();
#pragma unroll
    for (int ks = 0; ks < 2; ++ks) {
      const int kg = ks * 4 + (lane >> 4);
      short8 af[4], b1f[4], b3f[4];
#pragma unroll
      for (int m = 0; m < 4; ++m) {
        int row = wm * 64 + m * 16 + (lane & 15);
        af[m] = As[row * 8 + (kg ^ (row & 7))];
      }
#pragma unroll
      for (int n = 0; n < 4; ++n) {
        int row = wn * 64 + n * 16 + (lane & 15);
        int idx = row * 8 + (kg ^ (row & 7));
        b1f[n] = B1s[idx];
        b3f[n] = B3s[idx];
      }
#pragma unroll
      for (int m = 0; m < 4; ++m)
#pragma unroll
        for (int n = 0; n < 4; ++n) {
          acc1[m][n] = __builtin_amdgcn_mfma_f32_16x16x32_bf16(af[m], b1f[n], acc1[m][n], 0, 0, 0);
          acc3[m][n] = __builtin_amdgcn_mfma_f32_16x16x32_bf16(af[m], b3f[n], acc3[m][n], 0, 0, 0);
        }
    }
    __syncthreads();
  }

  const int obase = offs[e];
#pragma unroll
  for (int m = 0; m < 4; ++m)
#pragma unroll
    for (int r = 0; r < 4; ++r) {
      int i = by * 128 + wm * 64 + m * 16 + (lane >> 4) * 4 + r;
      if (i < n_e) {
        unsigned short* hp = h + (size_t)(obase + i) * INNER + n0 + wn * 64 + (lane & 15);
#pragma unroll
        for (int n = 0; n < 4; ++n) {
          float v1 = acc1[m][n][r];
          float v3 = acc3[m][n][r];
          float hv = __fdividef(v1, 1.f + __expf(-v1)) * v3;  // silu(v1)*v3
          hp[n * 16] = f2bf(hv);
        }
      }
    }
}

// ------- GEMM2: out[t] += wt * (h · w2^T) -----------------------------------
__global__ void __launch_bounds__(256, 2)
gemm2_kernel(const unsigned short* __restrict__ h, const float* __restrict__ w2,
             const int* __restrict__ cnt, const int* __restrict__ offs,
             const int* __restrict__ tok, const float* __restrict__ twt,
             float* __restrict__ out) {
  const int e = blockIdx.z;
  const int n_e = cnt[e];
  const int by = blockIdx.y;
  if (by * 128 >= n_e) return;
  const int n0 = blockIdx.x * 128;
  const int tid = threadIdx.x;
  const int lane = tid & 63;
  const int wid = tid >> 6;
  const int wm = wid >> 1, wn = wid & 1;
  const int obase = offs[e];

  __shared__ short8 As[1024];
  __shared__ short8 Bs[1024];

  const unsigned short* asrc[4];
  int adst[4];
#pragma unroll
  for (int rep = 0; rep < 4; ++rep) {
    int flat = rep * 256 + tid;
    int row = flat >> 3, g = flat & 7;
    int ri = by * 128 + row;
    if (ri >= n_e) ri = n_e - 1;
    asrc[rep] = h + (size_t)(obase + ri) * INNER + g * 8;
    adst[rep] = row * 8 + (g ^ (row & 7));
  }
  const float* w2e = w2 + (size_t)e * DIMSZ * INNER;
  const float* bsrc[2];
  int bd0[2], bd1[2];
#pragma unroll
  for (int rep = 0; rep < 2; ++rep) {
    int row = rep * 64 + (tid >> 2);
    int gb = (tid & 3) * 2;
    bsrc[rep] = w2e + (size_t)(n0 + row) * INNER + gb * 8;
    bd0[rep] = row * 8 + (gb ^ (row & 7));
    bd1[rep] = row * 8 + ((gb + 1) ^ (row & 7));
  }

  f32x4 acc[4][4] = {};

#pragma unroll 1
  for (int k0 = 0; k0 < INNER; k0 += 64) {
#pragma unroll
    for (int rep = 0; rep < 4; ++rep)
      As[adst[rep]] = *(const short8*)(asrc[rep] + k0);
#pragma unroll
    for (int rep = 0; rep < 2; ++rep) {
      const float4* p = (const float4*)(bsrc[rep] + k0);
      float4 a0 = p[0], a1 = p[1], a2 = p[2], a3 = p[3];
      Bs[bd0[rep]] = pack8(a0, a1);
      Bs[bd1[rep]] = pack8(a2, a3);
    }
    __syncthreads();
#pragma unroll
    for (int ks = 0; ks < 2; ++ks) {
      const int kg = ks * 4 + (lane >> 4);
      short8 af[4], bf[4];
#pragma unroll
      for (int m = 0; m < 4; ++m) {
        int row = wm * 64 + m * 16 + (lane & 15);
        af[m] = As[row * 8 + (kg ^ (row & 7))];
      }
#pragma unroll
      for (int n = 0; n < 4; ++n) {
        int row = wn * 64 + n * 16 + (lane & 15);
        bf[n] = Bs[row * 8 + (kg ^ (row & 7))];
      }
#pragma unroll
      for (int m = 0; m < 4; ++m)
#pragma unroll
        for (int n = 0; n < 4; ++n)
          acc[m][n] = __builtin_amdgcn_mfma_f32_16x16x32_bf16(af[m], bf[n], acc[m][n], 0, 0, 0);
    }
    __syncthreads();
  }

  // scatter: exactly 2 atomic adds per output element (commutative -> deterministic)
#pragma unroll
  for (int m = 0; m < 4; ++m)
#pragma unroll
    for (int r = 0; r < 4; ++r) {
      int i = by * 128 + wm * 64 + m * 16 + (lane >> 4) * 4 + r;
      if (i < n_e) {
        int t = tok[e * TOKS + i];
        float wt = twt[e * TOKS + i];
        float* op = out + (size_t)t * DIMSZ + n0 + wn * 64 + (lane & 15);
#pragma unroll
        for (int n = 0; n < 4; ++n)
          atomicAdd(op + n * 16, acc[m][n][r] * wt);
      }
    }
}

// ---------------------------------------------------------------------------
extern "C" void kernel_launch(void* const* d_in, const int* in_sizes, int n_in,
                              void* d_out, int out_size, void* d_ws, size_t ws_size,
                              hipStream_t stream) {
  (void)in_sizes; (void)n_in; (void)ws_size;
  const float* x  = (const float*)d_in[0];
  const float* gw = (const float*)d_in[1];
  const float* w1 = (const float*)d_in[2];
  const float* w2 = (const float*)d_in[3];
  const float* w3 = (const float*)d_in[4];
  float* out = (float*)d_out;

  char* ws = (char*)d_ws;
  int*            sel  = (int*)(ws);                      // 16 KB
  float*          wts  = (float*)(ws + (16 << 10));       // 16 KB
  int*            cnt  = (int*)(ws + (32 << 10));         // 32 B
  int*            offs = (int*)(ws + (32 << 10) + 64);    // 32 B
  int*            tok  = (int*)(ws + (33 << 10));         // 64 KB
  float*          twt  = (float*)(ws + (97 << 10));       // 64 KB
  unsigned short* xbf  = (unsigned short*)(ws + (1 << 20));   // 8.4 MB
  unsigned short* h    = (unsigned short*)(ws + (16 << 20));  // 46.2 MB

  hipMemsetAsync(out, 0, (size_t)out_size * sizeof(float), stream);
  cvtx_kernel<<<2048, 256, 0, stream>>>(x, xbf);
  router_kernel<<<TOKS, 64, 0, stream>>>(x, gw, sel, wts);
  compact_kernel<<<1, 512, 0, stream>>>(sel, wts, cnt, offs, tok, twt);
  gemm1_kernel<<<dim3(INNER / 128, TOKS / 128, NEXP), 256, 0, stream>>>(
      xbf, w1, w3, cnt, offs, tok, h);
  gemm2_kernel<<<dim3(DIMSZ / 128, TOKS / 128, NEXP), 256, 0, stream>>>(
      h, w2, cnt, offs, tok, twt, out);
}